// Round 5
// baseline (429.672 us; speedup 1.0000x reference)
//
#include <hip/hip_runtime.h>

#define V_SIZE 50257
#define B_SIZE 256
#define S_LEN  15
#define H_DIM  512
#define NBLK_LG 786   // ceil(50257/64)

typedef __attribute__((ext_vector_type(8))) short bf16x8;
typedef __attribute__((ext_vector_type(4))) float f32x4;

__device__ __forceinline__ unsigned short f2bf(float f) {
    unsigned int u = __float_as_uint(f);
    u += 0x7fffu + ((u >> 16) & 1u);   // RNE
    return (unsigned short)(u >> 16);
}

// ---------------------------------------------------------------------------
// K1: u[b,n] = sum_o h[b,o] * attn_W[o,n]   (fp32 vector; 67 MMAC total)
// ---------------------------------------------------------------------------
__global__ __launch_bounds__(256) void u_kernel(
    const float* __restrict__ hidden, const float* __restrict__ attn_W,
    float* __restrict__ u)
{
    __shared__ float h_s[16][H_DIM];
    const int tid = threadIdx.x;
    const int b0 = blockIdx.y * 16, n0 = blockIdx.x * 32;
    const float4* hv = (const float4*)(hidden + (size_t)b0 * H_DIM);
    float4* hs4 = (float4*)&h_s[0][0];
    #pragma unroll
    for (int i = 0; i < 8; ++i) hs4[tid + i * 256] = hv[tid + i * 256];
    __syncthreads();
    const int n = n0 + (tid & 31);
    const int m = (tid >> 5) * 2;
    float a0 = 0.f, a1 = 0.f;
    #pragma unroll 8
    for (int o = 0; o < H_DIM; ++o) {
        float w = attn_W[(size_t)o * H_DIM + n];
        a0 += h_s[m][o] * w;
        a1 += h_s[m + 1][o] * w;
    }
    u[(size_t)(b0 + m) * H_DIM + n] = a0;
    u[(size_t)(b0 + m + 1) * H_DIM + n] = a1;
}

// ---------------------------------------------------------------------------
// K2: per-b attention + bf16 prep of x=[emb,ctx] and h (enc staged in LDS)
// ---------------------------------------------------------------------------
__global__ __launch_bounds__(256) void attn_kernel(
    const float* __restrict__ hidden, const float* __restrict__ enc,
    const float* __restrict__ u, const int* __restrict__ tokens,
    const float* __restrict__ emb, float* __restrict__ attnw_out,
    unsigned short* __restrict__ x_bf, unsigned short* __restrict__ h_bf)
{
    const int b = blockIdx.x, tid = threadIdx.x;
    __shared__ float e_s[S_LEN][H_DIM];   // 30720 B
    __shared__ float u_s[H_DIM];
    __shared__ float sc_s[S_LEN];
    __shared__ float w_s[S_LEN];
    {
        const float4* ev = (const float4*)(enc + (size_t)b * S_LEN * H_DIM);
        float4* es4 = (float4*)&e_s[0][0];
        #pragma unroll
        for (int i = 0; i < 8; ++i) {
            int idx = i * 256 + tid;
            if (idx < S_LEN * H_DIM / 4) es4[idx] = ev[idx];
        }
    }
    u_s[tid]       = u[(size_t)b * H_DIM + tid];
    u_s[tid + 256] = u[(size_t)b * H_DIM + tid + 256];
    h_bf[(size_t)b * H_DIM + tid]       = f2bf(hidden[(size_t)b * H_DIM + tid]);
    h_bf[(size_t)b * H_DIM + tid + 256] = f2bf(hidden[(size_t)b * H_DIM + tid + 256]);
    const int tok = tokens[b];
    x_bf[(size_t)b * 2 * H_DIM + tid]       = f2bf(emb[(size_t)tok * H_DIM + tid]);
    x_bf[(size_t)b * 2 * H_DIM + tid + 256] = f2bf(emb[(size_t)tok * H_DIM + tid + 256]);
    __syncthreads();
    const int wave = tid >> 6, lane = tid & 63;
    for (int s = wave; s < S_LEN; s += 4) {
        float acc = 0.f;
        #pragma unroll
        for (int k = 0; k < H_DIM / 64; ++k)
            acc += e_s[s][lane + k * 64] * u_s[lane + k * 64];
        #pragma unroll
        for (int off = 32; off; off >>= 1) acc += __shfl_down(acc, off);
        if (lane == 0) sc_s[s] = acc;
    }
    __syncthreads();
    float mx = -1e30f;
    for (int s = 0; s < S_LEN; ++s) mx = fmaxf(mx, sc_s[s]);
    float sum = 0.f;
    for (int s = 0; s < S_LEN; ++s) sum += __expf(sc_s[s] - mx);
    const float inv = 1.f / sum;
    if (tid < S_LEN) {
        float w = __expf(sc_s[tid] - mx) * inv;
        w_s[tid] = w;
        attnw_out[b * S_LEN + tid] = w;
    }
    __syncthreads();
    #pragma unroll
    for (int hh = 0; hh < 2; ++hh) {
        int h = tid + hh * 256;
        float c = 0.f;
        #pragma unroll
        for (int s = 0; s < S_LEN; ++s)
            c += w_s[s] * e_s[s][h];
        x_bf[(size_t)b * 2 * H_DIM + H_DIM + h] = f2bf(c);
    }
}

// ---------------------------------------------------------------------------
// Small NT MFMA GEMM: C = A(bf16) * B(f32->bf16)^T + bias
// ---------------------------------------------------------------------------
struct GemmP {
    const unsigned short* A; const float* B; const float* bias; float* C;
    int N; int K;
};

template<int BM, int BN, int BK, int WR, int WC>
__global__ __launch_bounds__(256) void gemm_nt(GemmP p0, GemmP p1)
{
    GemmP p = (blockIdx.z == 0) ? p0 : p1;
    constexpr int LDA = BK + 8;
    __shared__ __align__(16) unsigned short As[BM][LDA];
    __shared__ __align__(16) unsigned short Bs[BN][LDA];
    const int tid = threadIdx.x;
    const int bn0 = blockIdx.x * BN;
    const int bm0 = blockIdx.y * BM;
    const int wave = tid >> 6, lane = tid & 63;
    const int wm = (wave / WC) * (BM / WR);
    const int wn = (wave % WC) * (BN / WC);
    constexpr int MF = BM / WR / 16, NF = BN / WC / 16;
    const int n16 = lane & 15, quad = lane >> 4;

    f32x4 acc[MF][NF] = {};

    for (int k0 = 0; k0 < p.K; k0 += BK) {
        #pragma unroll
        for (int it = 0; it < BM / 32; ++it) {
            int v = it * 256 + tid;
            int row = v >> 3, seg = v & 7;
            *(uint4*)&As[row][seg * 8] =
                *(const uint4*)(p.A + (size_t)(bm0 + row) * p.K + k0 + seg * 8);
        }
        #pragma unroll
        for (int it = 0; it < BN / 32; ++it) {
            int v = it * 256 + tid;
            int row = v >> 3, seg = v & 7;
            int gv = bn0 + row;
            float4 w0 = make_float4(0, 0, 0, 0), w1 = make_float4(0, 0, 0, 0);
            if (gv < p.N) {
                const float4* src = (const float4*)(p.B + (size_t)gv * p.K + k0 + seg * 8);
                w0 = src[0]; w1 = src[1];
            }
            uint4 pk;
            pk.x = (unsigned)f2bf(w0.x) | ((unsigned)f2bf(w0.y) << 16);
            pk.y = (unsigned)f2bf(w0.z) | ((unsigned)f2bf(w0.w) << 16);
            pk.z = (unsigned)f2bf(w1.x) | ((unsigned)f2bf(w1.y) << 16);
            pk.w = (unsigned)f2bf(w1.z) | ((unsigned)f2bf(w1.w) << 16);
            *(uint4*)&Bs[row][seg * 8] = pk;
        }
        __syncthreads();
        #pragma unroll
        for (int kk = 0; kk < BK; kk += 32) {
            bf16x8 af[MF], bfr[NF];
            #pragma unroll
            for (int i = 0; i < MF; ++i)
                af[i] = *(const bf16x8*)&As[wm + i * 16 + n16][kk + quad * 8];
            #pragma unroll
            for (int j = 0; j < NF; ++j)
                bfr[j] = *(const bf16x8*)&Bs[wn + j * 16 + n16][kk + quad * 8];
            #pragma unroll
            for (int i = 0; i < MF; ++i)
                #pragma unroll
                for (int j = 0; j < NF; ++j)
                    acc[i][j] = __builtin_amdgcn_mfma_f32_16x16x32_bf16(
                        af[i], bfr[j], acc[i][j], 0, 0, 0);
        }
        __syncthreads();
    }
    #pragma unroll
    for (int i = 0; i < MF; ++i) {
        const int r0 = bm0 + wm + i * 16 + quad * 4;
        #pragma unroll
        for (int j = 0; j < NF; ++j) {
            const int c = bn0 + wn + j * 16 + n16;
            if (c < p.N) {
                const float bv = p.bias[c];
                #pragma unroll
                for (int r = 0; r < 4; ++r)
                    p.C[(size_t)(r0 + r) * p.N + c] = acc[i][j][r] + bv;
            }
        }
    }
}

// ---------------------------------------------------------------------------
// Logits GEMM: C[256, V] = hnew_bf[256,512] @ out_W[V,512]^T + out_b.
// R4 restructure: NO LDS, NO BARRIERS. Shape (M=256,K=512) makes this a
// streaming op (128 FLOP per out_W byte); the only reuse LDS provided (B-tile
// shared by 4 waves of one CU) is equally served by L2. Each wave owns 64
// A-rows x 64 B-cols and streams K in 16 independent steps of
// {4 A-frag loads (L2), 8 B float4 loads (global), in-reg f2bf, 16 MFMA}.
// No lockstep: latency hides in per-wave MLP + VGPR-limited occupancy.
// OOB B-rows clamp to row 0 (loads safe); epilogue okj guards all writes.
// PART: per-block-contiguous softmax partials pm[block*256+row] (unchanged).
// ---------------------------------------------------------------------------
template<bool PART>
__global__ __launch_bounds__(256, 3) void gemm_lg(
    const unsigned short* __restrict__ A, const float* __restrict__ B,
    const float* __restrict__ bias, float* __restrict__ C,
    float* __restrict__ pm, float* __restrict__ ps)
{
    constexpr int BN = 64;
    const int tid = threadIdx.x;
    const int bn0 = blockIdx.x * BN;
    const int wave = tid >> 6, lane = tid & 63;
    const int wm = wave * 64;                 // wave-private 64 A-rows
    const int n16 = lane & 15, quad = lane >> 4;

    f32x4 acc[4][4] = {};
    const unsigned short* arow[4];
    #pragma unroll
    for (int i = 0; i < 4; ++i)
        arow[i] = A + (size_t)(wm + i * 16 + n16) * H_DIM;

    const float* brow[4];
    bool okj[4];
    #pragma unroll
    for (int j = 0; j < 4; ++j) {
        int gv = bn0 + j * 16 + n16;
        okj[j] = gv < V_SIZE;
        brow[j] = B + (size_t)(okj[j] ? gv : 0) * H_DIM;   // clamp: safe loads
    }

    #pragma unroll 4
    for (int kk = 0; kk < H_DIM; kk += 32) {
        bf16x8 af[4], bfr[4];
        #pragma unroll
        for (int i = 0; i < 4; ++i)
            af[i] = *(const bf16x8*)(arow[i] + kk + quad * 8);   // L2-hot A
        #pragma unroll
        for (int j = 0; j < 4; ++j) {
            const float4* src = (const float4*)(brow[j] + kk + quad * 8);
            float4 w0 = src[0], w1 = src[1];
            union { uint4 u; bf16x8 v; } cv;
            cv.u.x = (unsigned)f2bf(w0.x) | ((unsigned)f2bf(w0.y) << 16);
            cv.u.y = (unsigned)f2bf(w0.z) | ((unsigned)f2bf(w0.w) << 16);
            cv.u.z = (unsigned)f2bf(w1.x) | ((unsigned)f2bf(w1.y) << 16);
            cv.u.w = (unsigned)f2bf(w1.z) | ((unsigned)f2bf(w1.w) << 16);
            bfr[j] = cv.v;
        }
        #pragma unroll
        for (int i = 0; i < 4; ++i)
            #pragma unroll
            for (int j = 0; j < 4; ++j)
                acc[i][j] = __builtin_amdgcn_mfma_f32_16x16x32_bf16(
                    af[i], bfr[j], acc[i][j], 0, 0, 0);
    }

    // epilogue
    int cj[4]; float bvv[4];
    #pragma unroll
    for (int j = 0; j < 4; ++j) {
        cj[j] = bn0 + j * 16 + n16;
        bvv[j] = okj[j] ? bias[cj[j]] : 0.f;
    }
    #pragma unroll
    for (int i = 0; i < 4; ++i) {
        const int r0 = wm + i * 16 + quad * 4;
        if (PART) {
            #pragma unroll
            for (int r = 0; r < 4; ++r) {
                float m = -1e30f;
                #pragma unroll
                for (int j = 0; j < 4; ++j)
                    if (okj[j]) m = fmaxf(m, acc[i][j][r] + bvv[j]);
                #pragma unroll
                for (int d = 1; d < 16; d <<= 1) m = fmaxf(m, __shfl_xor(m, d));
                float s = 0.f;
                #pragma unroll
                for (int j = 0; j < 4; ++j)
                    if (okj[j]) s += __expf(acc[i][j][r] + bvv[j] - m);
                #pragma unroll
                for (int d = 1; d < 16; d <<= 1) s += __shfl_xor(s, d);
                if (n16 == 0) {
                    pm[(size_t)blockIdx.x * B_SIZE + r0 + r] = m;
                    ps[(size_t)blockIdx.x * B_SIZE + r0 + r] = s;
                }
            }
        }
        #pragma unroll
        for (int j = 0; j < 4; ++j) if (okj[j]) {
            #pragma unroll
            for (int r = 0; r < 4; ++r)
                C[(size_t)(r0 + r) * V_SIZE + cj[j]] = acc[i][j][r] + bvv[j];
        }
    }
}

// ---------------------------------------------------------------------------
// K3c: GRU gate math (fp32), writes h_new (f32 to d_out) + bf16 copy for GEMM
// ---------------------------------------------------------------------------
__global__ __launch_bounds__(256) void gru_kernel(
    const float* __restrict__ gi, const float* __restrict__ gh,
    const float* __restrict__ hidden, float* __restrict__ hnew_out,
    unsigned short* __restrict__ hnew_bf)
{
    const int idx = blockIdx.x * 256 + threadIdx.x;   // < 131072
    const int b = idx >> 9, h = idx & 511;
    const float* gib = gi + (size_t)b * 3 * H_DIM;
    const float* ghb = gh + (size_t)b * 3 * H_DIM;
    float r = 1.f / (1.f + __expf(-(gib[h] + ghb[h])));
    float z = 1.f / (1.f + __expf(-(gib[H_DIM + h] + ghb[H_DIM + h])));
    float n = gib[2 * H_DIM + h] + r * ghb[2 * H_DIM + h];
    n = 1.f - 2.f / (1.f + __expf(2.f * n));          // tanh
    float hp = hidden[idx];
    float hn = (1.f - z) * n + z * hp;
    hnew_out[idx] = hn;
    hnew_bf[idx] = f2bf(hn);
}

// ---------------------------------------------------------------------------
// K5: combine 786 partials/row -> lse, subtract over this block's V-half.
// grid (256 rows, 2 halves), block 1024, float4-vectorized subtract.
// ---------------------------------------------------------------------------
__global__ __launch_bounds__(1024) void finalize_kernel(
    float* __restrict__ logits, const float* __restrict__ pm,
    const float* __restrict__ ps)
{
    const int b = blockIdx.x, tid = threadIdx.x;
    float m = -1e30f, s = 0.f;
    for (int i = tid; i < NBLK_LG; i += 1024) {
        float mm = pm[(size_t)i * B_SIZE + b], ss = ps[(size_t)i * B_SIZE + b];
        float nm = fmaxf(m, mm);
        s = s * __expf(m - nm) + ss * __expf(mm - nm);
        m = nm;
    }
    const int lane = tid & 63, wave = tid >> 6;
    #pragma unroll
    for (int off = 32; off; off >>= 1) {
        float m2 = __shfl_down(m, off), s2 = __shfl_down(s, off);
        float nm = fmaxf(m, m2);
        s = s * __expf(m - nm) + s2 * __expf(m2 - nm);
        m = nm;
    }
    __shared__ float msh[16], ssh[16], lse_sh;
    if (lane == 0) { msh[wave] = m; ssh[wave] = s; }
    __syncthreads();
    if (tid == 0) {
        float M = msh[0], S = ssh[0];
        for (int w = 1; w < 16; ++w) {
            float nm = fmaxf(M, msh[w]);
            S = S * __expf(M - nm) + ssh[w] * __expf(msh[w] - nm);
            M = nm;
        }
        lse_sh = M + logf(S);
    }
    __syncthreads();
    const float lse = lse_sh;
    constexpr int HALF = 25132;               // multiple of 4
    const int start = blockIdx.y * HALF;
    const int end = min(V_SIZE, start + HALF);
    float* p0 = logits + (size_t)b * V_SIZE + start;
    const int n = end - start;
    const int mis = (int)(((uintptr_t)p0 >> 2) & 3);
    int pre = mis ? (4 - mis) : 0; if (pre > n) pre = n;
    if (tid < pre) p0[tid] -= lse;
    const int nvec = (n - pre) >> 2;
    float4* rv = (float4*)(p0 + pre);
    for (int i = tid; i < nvec; i += 1024) {
        float4 v = rv[i];
        v.x -= lse; v.y -= lse; v.z -= lse; v.w -= lse;
        rv[i] = v;
    }
    const int rem = n - pre - (nvec << 2);
    if (tid < rem) p0[pre + (nvec << 2) + tid] -= lse;
}

// fallback: two-pass log-softmax (only if ws too small for partials)
__global__ __launch_bounds__(1024) void logsoftmax_kernel(float* __restrict__ logits)
{
    const int b = blockIdx.x, tid = threadIdx.x;
    float* row = logits + (size_t)b * V_SIZE;
    float m = -1e30f, s = 0.f;
    for (int c = tid; c < V_SIZE; c += 1024) {
        float x = row[c];
        float nm = fmaxf(m, x);
        s = s * __expf(m - nm) + __expf(x - nm);
        m = nm;
    }
    const int lane = tid & 63, wave = tid >> 6;
    #pragma unroll
    for (int off = 32; off; off >>= 1) {
        float m2 = __shfl_down(m, off), s2 = __shfl_down(s, off);
        float nm = fmaxf(m, m2);
        s = s * __expf(m - nm) + s2 * __expf(m2 - nm);
        m = nm;
    }
    __shared__ float msh[16], ssh[16], lse_sh;
    if (lane == 0) { msh[wave] = m; ssh[wave] = s; }
    __syncthreads();
    if (tid == 0) {
        float M = msh[0], S = ssh[0];
        for (int w = 1; w < 16; ++w) {
            float nm = fmaxf(M, msh[w]);
            S = S * __expf(M - nm) + ssh[w] * __expf(msh[w] - nm);
            M = nm;
        }
        lse_sh = M + logf(S);
    }
    __syncthreads();
    const float lse = lse_sh;
    for (int c = tid; c < V_SIZE; c += 1024) row[c] -= lse;
}

// ---------------------------------------------------------------------------
// workspace layout (bytes)
// ---------------------------------------------------------------------------
constexpr size_t OFF_U      = 0;         // 256*512*4  = 524288
constexpr size_t OFF_XBF    = 524288;    // 256*1024*2 = 524288
constexpr size_t OFF_HBF    = 1048576;   // 256*512*2  = 262144
constexpr size_t OFF_HNEWBF = 1310720;   // 262144
constexpr size_t OFF_GI     = 1572864;   // 256*1536*4 = 1572864
constexpr size_t OFF_GH     = 3145728;   // 1572864
constexpr size_t OFF_PM     = 4718592;   // 786*256*4  = 804864
constexpr size_t OFF_PS     = 5523456;   // 804864
constexpr size_t WS_NEED    = 6328320;

extern "C" void kernel_launch(void* const* d_in, const int* in_sizes, int n_in,
                              void* d_out, int out_size, void* d_ws, size_t ws_size,
                              hipStream_t stream) {
    const int*   tokens = (const int*)d_in[0];
    const float* hidden = (const float*)d_in[1];
    const float* enc    = (const float*)d_in[2];
    const float* emb    = (const float*)d_in[3];
    const float* attn_W = (const float*)d_in[4];
    // d_in[5] = attn_b: constant across s -> cancels in softmax; unused
    const float* W_ih   = (const float*)d_in[6];
    const float* W_hh   = (const float*)d_in[7];
    const float* b_ih   = (const float*)d_in[8];
    const float* b_hh   = (const float*)d_in[9];
    const float* out_W  = (const float*)d_in[10];
    const float* out_b  = (const float*)d_in[11];

    float* out = (float*)d_out;
    float* logp      = out;                                   // [256][50257]
    float* hnew_out  = out + (size_t)B_SIZE * V_SIZE;         // [256][512]
    float* attnw_out = hnew_out + (size_t)B_SIZE * H_DIM;     // [256][15]

    char* ws = (char*)d_ws;
    float*          u_ws    = (float*)(ws + OFF_U);
    unsigned short* x_bf    = (unsigned short*)(ws + OFF_XBF);
    unsigned short* h_bf    = (unsigned short*)(ws + OFF_HBF);
    unsigned short* hnew_bf = (unsigned short*)(ws + OFF_HNEWBF);
    float*          gi_ws   = (float*)(ws + OFF_GI);
    float*          gh_ws   = (float*)(ws + OFF_GH);
    float*          pm_ws   = (float*)(ws + OFF_PM);
    float*          ps_ws   = (float*)(ws + OFF_PS);

    u_kernel<<<dim3(16, 16), 256, 0, stream>>>(hidden, attn_W, u_ws);
    attn_kernel<<<dim3(256), 256, 0, stream>>>(hidden, enc, u_ws, tokens, emb,
                                               attnw_out, x_bf, h_bf);
    GemmP gi_p { x_bf, W_ih, b_ih, gi_ws, 3 * H_DIM, 2 * H_DIM };
    GemmP gh_p { h_bf, W_hh, b_hh, gh_ws, 3 * H_DIM, H_DIM };
    gemm_nt<64, 64, 64, 2, 2><<<dim3(24, 4, 2), 256, 0, stream>>>(gi_p, gh_p);
    gru_kernel<<<dim3(512), 256, 0, stream>>>(gi_ws, gh_ws, hidden, hnew_out, hnew_bf);

    if (ws_size >= WS_NEED) {
        gemm_lg<true><<<dim3(NBLK_LG), 256, 0, stream>>>(
            hnew_bf, out_W, out_b, logp, pm_ws, ps_ws);
        finalize_kernel<<<dim3(256, 2), 1024, 0, stream>>>(logp, pm_ws, ps_ws);
    } else {
        gemm_lg<false><<<dim3(NBLK_LG), 256, 0, stream>>>(
            hnew_bf, out_W, out_b, logp, nullptr, nullptr);
        logsoftmax_kernel<<<dim3(256), 1024, 0, stream>>>(logp);
    }
}

// Round 6
// 368.832 us; speedup vs baseline: 1.1650x; 1.1650x over previous
//
#include <hip/hip_runtime.h>

#define V_SIZE 50257
#define B_SIZE 256
#define S_LEN  15
#define H_DIM  512
#define NBLK_LG 786   // ceil(50257/64)

typedef __attribute__((ext_vector_type(8))) short bf16x8;
typedef __attribute__((ext_vector_type(4))) float f32x4;

__device__ __forceinline__ unsigned short f2bf(float f) {
    unsigned int u = __float_as_uint(f);
    u += 0x7fffu + ((u >> 16) & 1u);   // RNE
    return (unsigned short)(u >> 16);
}

// ---------------------------------------------------------------------------
// K2 (fused R5): per-b attention with u = h@attn_W computed INLINE (u_kernel
// removed). attn_W col-read is 64-lane coalesced (256B/wave/o); 1MB/block from
// L2/L3 (attn_W is L2-resident per XCD). Also writes bf16 x=[emb,ctx], h.
// ---------------------------------------------------------------------------
__global__ __launch_bounds__(256) void attn_kernel(
    const float* __restrict__ hidden, const float* __restrict__ enc,
    const int* __restrict__ tokens, const float* __restrict__ emb,
    const float* __restrict__ attn_W, float* __restrict__ attnw_out,
    unsigned short* __restrict__ x_bf, unsigned short* __restrict__ h_bf)
{
    const int b = blockIdx.x, tid = threadIdx.x;
    __shared__ float e_s[S_LEN][H_DIM];   // 30720 B
    __shared__ float h_sh[H_DIM];
    __shared__ float u_s[H_DIM];
    __shared__ float sc_s[S_LEN];
    __shared__ float w_s[S_LEN];
    {
        const float4* ev = (const float4*)(enc + (size_t)b * S_LEN * H_DIM);
        float4* es4 = (float4*)&e_s[0][0];
        #pragma unroll
        for (int i = 0; i < 8; ++i) {
            int idx = i * 256 + tid;
            if (idx < S_LEN * H_DIM / 4) es4[idx] = ev[idx];
        }
    }
    const float hv0 = hidden[(size_t)b * H_DIM + tid];
    const float hv1 = hidden[(size_t)b * H_DIM + tid + 256];
    h_sh[tid] = hv0; h_sh[tid + 256] = hv1;
    h_bf[(size_t)b * H_DIM + tid]       = f2bf(hv0);
    h_bf[(size_t)b * H_DIM + tid + 256] = f2bf(hv1);
    const int tok = tokens[b];
    x_bf[(size_t)b * 2 * H_DIM + tid]       = f2bf(emb[(size_t)tok * H_DIM + tid]);
    x_bf[(size_t)b * 2 * H_DIM + tid + 256] = f2bf(emb[(size_t)tok * H_DIM + tid + 256]);
    __syncthreads();
    // u[n] = sum_o h[o] * attn_W[o][n], n = tid and tid+256
    {
        float u0 = 0.f, u1 = 0.f;
        #pragma unroll 8
        for (int o = 0; o < H_DIM; ++o) {
            const float hs = h_sh[o];                    // LDS broadcast
            u0 += hs * attn_W[(size_t)o * H_DIM + tid];
            u1 += hs * attn_W[(size_t)o * H_DIM + tid + 256];
        }
        u_s[tid] = u0; u_s[tid + 256] = u1;
    }
    __syncthreads();
    const int wave = tid >> 6, lane = tid & 63;
    for (int s = wave; s < S_LEN; s += 4) {
        float acc = 0.f;
        #pragma unroll
        for (int k = 0; k < H_DIM / 64; ++k)
            acc += e_s[s][lane + k * 64] * u_s[lane + k * 64];
        #pragma unroll
        for (int off = 32; off; off >>= 1) acc += __shfl_down(acc, off);
        if (lane == 0) sc_s[s] = acc;
    }
    __syncthreads();
    float mx = -1e30f;
    for (int s = 0; s < S_LEN; ++s) mx = fmaxf(mx, sc_s[s]);
    float sum = 0.f;
    for (int s = 0; s < S_LEN; ++s) sum += __expf(sc_s[s] - mx);
    const float inv = 1.f / sum;
    if (tid < S_LEN) {
        float w = __expf(sc_s[tid] - mx) * inv;
        w_s[tid] = w;
        attnw_out[b * S_LEN + tid] = w;
    }
    __syncthreads();
    #pragma unroll
    for (int hh = 0; hh < 2; ++hh) {
        int h = tid + hh * 256;
        float c = 0.f;
        #pragma unroll
        for (int s = 0; s < S_LEN; ++s)
            c += w_s[s] * e_s[s][h];
        x_bf[(size_t)b * 2 * H_DIM + H_DIM + h] = f2bf(c);
    }
}

// ---------------------------------------------------------------------------
// Small NT MFMA GEMM: C = A(bf16) * B(f32->bf16)^T + bias
// ---------------------------------------------------------------------------
struct GemmP {
    const unsigned short* A; const float* B; const float* bias; float* C;
    int N; int K;
};

template<int BM, int BN, int BK, int WR, int WC>
__global__ __launch_bounds__(256) void gemm_nt(GemmP p0, GemmP p1)
{
    GemmP p = (blockIdx.z == 0) ? p0 : p1;
    constexpr int LDA = BK + 8;
    __shared__ __align__(16) unsigned short As[BM][LDA];
    __shared__ __align__(16) unsigned short Bs[BN][LDA];
    const int tid = threadIdx.x;
    const int bn0 = blockIdx.x * BN;
    const int bm0 = blockIdx.y * BM;
    const int wave = tid >> 6, lane = tid & 63;
    const int wm = (wave / WC) * (BM / WR);
    const int wn = (wave % WC) * (BN / WC);
    constexpr int MF = BM / WR / 16, NF = BN / WC / 16;
    const int n16 = lane & 15, quad = lane >> 4;

    f32x4 acc[MF][NF] = {};

    for (int k0 = 0; k0 < p.K; k0 += BK) {
        #pragma unroll
        for (int it = 0; it < BM / 32; ++it) {
            int v = it * 256 + tid;
            int row = v >> 3, seg = v & 7;
            *(uint4*)&As[row][seg * 8] =
                *(const uint4*)(p.A + (size_t)(bm0 + row) * p.K + k0 + seg * 8);
        }
        #pragma unroll
        for (int it = 0; it < BN / 32; ++it) {
            int v = it * 256 + tid;
            int row = v >> 3, seg = v & 7;
            int gv = bn0 + row;
            float4 w0 = make_float4(0, 0, 0, 0), w1 = make_float4(0, 0, 0, 0);
            if (gv < p.N) {
                const float4* src = (const float4*)(p.B + (size_t)gv * p.K + k0 + seg * 8);
                w0 = src[0]; w1 = src[1];
            }
            uint4 pk;
            pk.x = (unsigned)f2bf(w0.x) | ((unsigned)f2bf(w0.y) << 16);
            pk.y = (unsigned)f2bf(w0.z) | ((unsigned)f2bf(w0.w) << 16);
            pk.z = (unsigned)f2bf(w1.x) | ((unsigned)f2bf(w1.y) << 16);
            pk.w = (unsigned)f2bf(w1.z) | ((unsigned)f2bf(w1.w) << 16);
            *(uint4*)&Bs[row][seg * 8] = pk;
        }
        __syncthreads();
        #pragma unroll
        for (int kk = 0; kk < BK; kk += 32) {
            bf16x8 af[MF], bfr[NF];
            #pragma unroll
            for (int i = 0; i < MF; ++i)
                af[i] = *(const bf16x8*)&As[wm + i * 16 + n16][kk + quad * 8];
            #pragma unroll
            for (int j = 0; j < NF; ++j)
                bfr[j] = *(const bf16x8*)&Bs[wn + j * 16 + n16][kk + quad * 8];
            #pragma unroll
            for (int i = 0; i < MF; ++i)
                #pragma unroll
                for (int j = 0; j < NF; ++j)
                    acc[i][j] = __builtin_amdgcn_mfma_f32_16x16x32_bf16(
                        af[i], bfr[j], acc[i][j], 0, 0, 0);
        }
        __syncthreads();
    }
    #pragma unroll
    for (int i = 0; i < MF; ++i) {
        const int r0 = bm0 + wm + i * 16 + quad * 4;
        #pragma unroll
        for (int j = 0; j < NF; ++j) {
            const int c = bn0 + wn + j * 16 + n16;
            if (c < p.N) {
                const float bv = p.bias[c];
                #pragma unroll
                for (int r = 0; r < 4; ++r)
                    p.C[(size_t)(r0 + r) * p.N + c] = acc[i][j][r] + bv;
            }
        }
    }
}

// ---------------------------------------------------------------------------
// Logits GEMM (r4 M-split structure, proven 83us) split into TWO V-half
// launches (bx0 = 0 / 393) for per-dispatch profiling attribution; each half
// is ~43-46us so any hidden >46us kernel must surface in the top-5.
// 786 blocks/launch: 784 co-XCD-paired (49 groups of 16: ids g*16+s and
// g*16+s+8 share XCD id%8 and the same bx, by=0/1) + 2 tail for bx off 392.
// BM=128 per block (wave owns 32 rows, acc[2][4]); B staged in LDS (BK=128).
// pm/ps layout pm[bx*256+row] unchanged (bx global).
// ---------------------------------------------------------------------------
template<bool PART>
__global__ __launch_bounds__(256, 4) void gemm_lg(
    const unsigned short* __restrict__ A, const float* __restrict__ B,
    const float* __restrict__ bias, float* __restrict__ C,
    float* __restrict__ pm, float* __restrict__ ps, int bx0)
{
    constexpr int BN = 64, BK = 128;
    constexpr int LDB = BK + 8;              // 136 shorts = 272B pitch
    __shared__ __align__(16) unsigned short Bs[BN][LDB];
    const int tid = threadIdx.x;
    const int blk = blockIdx.x;
    int bx, by;
    if (blk < 784) { int g = blk >> 4, s = blk & 15; bx = bx0 + g * 8 + (s & 7); by = s >> 3; }
    else           { int s = blk - 784;              bx = bx0 + 392;             by = s;      }
    const int bn0 = bx * BN;
    const int m0  = by * 128;                 // this block's 128 A-rows
    const int wave = tid >> 6, lane = tid & 63;
    const int wm = wave * 32;                 // wave-private 32 A-rows
    const int n16 = lane & 15, quad = lane >> 4;

    f32x4 acc[2][4] = {};
    const unsigned short* arow[2];
    #pragma unroll
    for (int i = 0; i < 2; ++i)
        arow[i] = A + (size_t)(m0 + wm + i * 16 + n16) * H_DIM;

    for (int k0 = 0; k0 < H_DIM; k0 += BK) {
        // stage B: 64 rows x 128 k (f32) -> bf16 LDS. 1024 v-slots of 8 f32.
        #pragma unroll
        for (int it = 0; it < 4; ++it) {
            int v = it * 256 + tid;
            int row = v >> 4, seg = v & 15;
            int gv = bn0 + row;
            float4 w0 = make_float4(0, 0, 0, 0), w1 = make_float4(0, 0, 0, 0);
            if (gv < V_SIZE) {
                const float4* src = (const float4*)(B + (size_t)gv * H_DIM + k0 + seg * 8);
                w0 = src[0]; w1 = src[1];
            }
            uint4 pk;
            pk.x = (unsigned)f2bf(w0.x) | ((unsigned)f2bf(w0.y) << 16);
            pk.y = (unsigned)f2bf(w0.z) | ((unsigned)f2bf(w0.w) << 16);
            pk.z = (unsigned)f2bf(w1.x) | ((unsigned)f2bf(w1.y) << 16);
            pk.w = (unsigned)f2bf(w1.z) | ((unsigned)f2bf(w1.w) << 16);
            *(uint4*)&Bs[row][seg * 8] = pk;
        }
        __syncthreads();
        #pragma unroll
        for (int kk = 0; kk < BK; kk += 32) {
            bf16x8 af[2], bfr[4];
            #pragma unroll
            for (int i = 0; i < 2; ++i)
                af[i] = *(const bf16x8*)(arow[i] + k0 + kk + quad * 8);  // global, L2-hit
            #pragma unroll
            for (int j = 0; j < 4; ++j)
                bfr[j] = *(const bf16x8*)&Bs[j * 16 + n16][kk + quad * 8];
            #pragma unroll
            for (int i = 0; i < 2; ++i)
                #pragma unroll
                for (int j = 0; j < 4; ++j)
                    acc[i][j] = __builtin_amdgcn_mfma_f32_16x16x32_bf16(
                        af[i], bfr[j], acc[i][j], 0, 0, 0);
        }
        __syncthreads();
    }

    // epilogue
    int cj[4]; float bvv[4]; bool okj[4];
    #pragma unroll
    for (int j = 0; j < 4; ++j) {
        cj[j] = bn0 + j * 16 + n16;
        okj[j] = cj[j] < V_SIZE;
        bvv[j] = okj[j] ? bias[cj[j]] : 0.f;
    }
    #pragma unroll
    for (int i = 0; i < 2; ++i) {
        const int r0 = wm + i * 16 + quad * 4;         // local row in [0,128)
        if (PART) {
            #pragma unroll
            for (int r = 0; r < 4; ++r) {
                float m = -1e30f;
                #pragma unroll
                for (int j = 0; j < 4; ++j)
                    if (okj[j]) m = fmaxf(m, acc[i][j][r] + bvv[j]);
                #pragma unroll
                for (int d = 1; d < 16; d <<= 1) m = fmaxf(m, __shfl_xor(m, d));
                float s = 0.f;
                #pragma unroll
                for (int j = 0; j < 4; ++j)
                    if (okj[j]) s += __expf(acc[i][j][r] + bvv[j] - m);
                #pragma unroll
                for (int d = 1; d < 16; d <<= 1) s += __shfl_xor(s, d);
                if (n16 == 0) {
                    pm[(size_t)bx * B_SIZE + m0 + r0 + r] = m;
                    ps[(size_t)bx * B_SIZE + m0 + r0 + r] = s;
                }
            }
        }
        #pragma unroll
        for (int j = 0; j < 4; ++j) if (okj[j]) {
            #pragma unroll
            for (int r = 0; r < 4; ++r)
                C[(size_t)(m0 + r0 + r) * V_SIZE + cj[j]] = acc[i][j][r] + bvv[j];
        }
    }
}

// ---------------------------------------------------------------------------
// K3c: GRU gate math (fp32), writes h_new (f32 to d_out) + bf16 copy for GEMM
// ---------------------------------------------------------------------------
__global__ __launch_bounds__(256) void gru_kernel(
    const float* __restrict__ gi, const float* __restrict__ gh,
    const float* __restrict__ hidden, float* __restrict__ hnew_out,
    unsigned short* __restrict__ hnew_bf)
{
    const int idx = blockIdx.x * 256 + threadIdx.x;   // < 131072
    const int b = idx >> 9, h = idx & 511;
    const float* gib = gi + (size_t)b * 3 * H_DIM;
    const float* ghb = gh + (size_t)b * 3 * H_DIM;
    float r = 1.f / (1.f + __expf(-(gib[h] + ghb[h])));
    float z = 1.f / (1.f + __expf(-(gib[H_DIM + h] + ghb[H_DIM + h])));
    float n = gib[2 * H_DIM + h] + r * ghb[2 * H_DIM + h];
    n = 1.f - 2.f / (1.f + __expf(2.f * n));          // tanh
    float hp = hidden[idx];
    float hn = (1.f - z) * n + z * hp;
    hnew_out[idx] = hn;
    hnew_bf[idx] = f2bf(hn);
}

// ---------------------------------------------------------------------------
// K5: combine 786 partials/row -> lse, subtract over this block's V-half.
// grid (256 rows, 2 halves), block 1024, float4-vectorized subtract.
// ---------------------------------------------------------------------------
__global__ __launch_bounds__(1024) void finalize_kernel(
    float* __restrict__ logits, const float* __restrict__ pm,
    const float* __restrict__ ps)
{
    const int b = blockIdx.x, tid = threadIdx.x;
    float m = -1e30f, s = 0.f;
    for (int i = tid; i < NBLK_LG; i += 1024) {
        float mm = pm[(size_t)i * B_SIZE + b], ss = ps[(size_t)i * B_SIZE + b];
        float nm = fmaxf(m, mm);
        s = s * __expf(m - nm) + ss * __expf(mm - nm);
        m = nm;
    }
    const int lane = tid & 63, wave = tid >> 6;
    #pragma unroll
    for (int off = 32; off; off >>= 1) {
        float m2 = __shfl_down(m, off), s2 = __shfl_down(s, off);
        float nm = fmaxf(m, m2);
        s = s * __expf(m - nm) + s2 * __expf(m2 - nm);
        m = nm;
    }
    __shared__ float msh[16], ssh[16], lse_sh;
    if (lane == 0) { msh[wave] = m; ssh[wave] = s; }
    __syncthreads();
    if (tid == 0) {
        float M = msh[0], S = ssh[0];
        for (int w = 1; w < 16; ++w) {
            float nm = fmaxf(M, msh[w]);
            S = S * __expf(M - nm) + ssh[w] * __expf(msh[w] - nm);
            M = nm;
        }
        lse_sh = M + logf(S);
    }
    __syncthreads();
    const float lse = lse_sh;
    constexpr int HALF = 25132;               // multiple of 4
    const int start = blockIdx.y * HALF;
    const int end = min(V_SIZE, start + HALF);
    float* p0 = logits + (size_t)b * V_SIZE + start;
    const int n = end - start;
    const int mis = (int)(((uintptr_t)p0 >> 2) & 3);
    int pre = mis ? (4 - mis) : 0; if (pre > n) pre = n;
    if (tid < pre) p0[tid] -= lse;
    const int nvec = (n - pre) >> 2;
    float4* rv = (float4*)(p0 + pre);
    for (int i = tid; i < nvec; i += 1024) {
        float4 v = rv[i];
        v.x -= lse; v.y -= lse; v.z -= lse; v.w -= lse;
        rv[i] = v;
    }
    const int rem = n - pre - (nvec << 2);
    if (tid < rem) p0[pre + (nvec << 2) + tid] -= lse;
}

// fallback: two-pass log-softmax (only if ws too small for partials)
__global__ __launch_bounds__(1024) void logsoftmax_kernel(float* __restrict__ logits)
{
    const int b = blockIdx.x, tid = threadIdx.x;
    float* row = logits + (size_t)b * V_SIZE;
    float m = -1e30f, s = 0.f;
    for (int c = tid; c < V_SIZE; c += 1024) {
        float x = row[c];
        float nm = fmaxf(m, x);
        s = s * __expf(m - nm) + __expf(x - nm);
        m = nm;
    }
    const int lane = tid & 63, wave = tid >> 6;
    #pragma unroll
    for (int off = 32; off; off >>= 1) {
        float m2 = __shfl_down(m, off), s2 = __shfl_down(s, off);
        float nm = fmaxf(m, m2);
        s = s * __expf(m - nm) + s2 * __expf(m2 - nm);
        m = nm;
    }
    __shared__ float msh[16], ssh[16], lse_sh;
    if (lane == 0) { msh[wave] = m; ssh[wave] = s; }
    __syncthreads();
    if (tid == 0) {
        float M = msh[0], S = ssh[0];
        for (int w = 1; w < 16; ++w) {
            float nm = fmaxf(M, msh[w]);
            S = S * __expf(M - nm) + ssh[w] * __expf(msh[w] - nm);
            M = nm;
        }
        lse_sh = M + logf(S);
    }
    __syncthreads();
    const float lse = lse_sh;
    for (int c = tid; c < V_SIZE; c += 1024) row[c] -= lse;
}

// ---------------------------------------------------------------------------
// workspace layout (bytes)
// ---------------------------------------------------------------------------
constexpr size_t OFF_U      = 0;         // 256*512*4  = 524288 (unused since R5)
constexpr size_t OFF_XBF    = 524288;    // 256*1024*2 = 524288
constexpr size_t OFF_HBF    = 1048576;   // 256*512*2  = 262144
constexpr size_t OFF_HNEWBF = 1310720;   // 262144
constexpr size_t OFF_GI     = 1572864;   // 256*1536*4 = 1572864
constexpr size_t OFF_GH     = 3145728;   // 1572864
constexpr size_t OFF_PM     = 4718592;   // 786*256*4  = 804864
constexpr size_t OFF_PS     = 5523456;   // 804864
constexpr size_t WS_NEED    = 6328320;

extern "C" void kernel_launch(void* const* d_in, const int* in_sizes, int n_in,
                              void* d_out, int out_size, void* d_ws, size_t ws_size,
                              hipStream_t stream) {
    const int*   tokens = (const int*)d_in[0];
    const float* hidden = (const float*)d_in[1];
    const float* enc    = (const float*)d_in[2];
    const float* emb    = (const float*)d_in[3];
    const float* attn_W = (const float*)d_in[4];
    // d_in[5] = attn_b: constant across s -> cancels in softmax; unused
    const float* W_ih   = (const float*)d_in[6];
    const float* W_hh   = (const float*)d_in[7];
    const float* b_ih   = (const float*)d_in[8];
    const float* b_hh   = (const float*)d_in[9];
    const float* out_W  = (const float*)d_in[10];
    const float* out_b  = (const float*)d_in[11];

    float* out = (float*)d_out;
    float* logp      = out;                                   // [256][50257]
    float* hnew_out  = out + (size_t)B_SIZE * V_SIZE;         // [256][512]
    float* attnw_out = hnew_out + (size_t)B_SIZE * H_DIM;     // [256][15]

    char* ws = (char*)d_ws;
    unsigned short* x_bf    = (unsigned short*)(ws + OFF_XBF);
    unsigned short* h_bf    = (unsigned short*)(ws + OFF_HBF);
    unsigned short* hnew_bf = (unsigned short*)(ws + OFF_HNEWBF);
    float*          gi_ws   = (float*)(ws + OFF_GI);
    float*          gh_ws   = (float*)(ws + OFF_GH);
    float*          pm_ws   = (float*)(ws + OFF_PM);
    float*          ps_ws   = (float*)(ws + OFF_PS);

    attn_kernel<<<dim3(256), 256, 0, stream>>>(hidden, enc, tokens, emb, attn_W,
                                               attnw_out, x_bf, h_bf);
    GemmP gi_p { x_bf, W_ih, b_ih, gi_ws, 3 * H_DIM, 2 * H_DIM };
    GemmP gh_p { h_bf, W_hh, b_hh, gh_ws, 3 * H_DIM, H_DIM };
    gemm_nt<64, 64, 64, 2, 2><<<dim3(24, 4, 2), 256, 0, stream>>>(gi_p, gh_p);
    gru_kernel<<<dim3(512), 256, 0, stream>>>(gi_ws, gh_ws, hidden, hnew_out, hnew_bf);

    if (ws_size >= WS_NEED) {
        gemm_lg<true><<<dim3(NBLK_LG), 256, 0, stream>>>(
            hnew_bf, out_W, out_b, logp, pm_ws, ps_ws, 0);
        gemm_lg<true><<<dim3(NBLK_LG), 256, 0, stream>>>(
            hnew_bf, out_W, out_b, logp, pm_ws, ps_ws, 393);
        finalize_kernel<<<dim3(256, 2), 1024, 0, stream>>>(logp, pm_ws, ps_ws);
    } else {
        gemm_lg<false><<<dim3(NBLK_LG), 256, 0, stream>>>(
            hnew_bf, out_W, out_b, logp, nullptr, nullptr, 0);
        gemm_lg<false><<<dim3(NBLK_LG), 256, 0, stream>>>(
            hnew_bf, out_W, out_b, logp, nullptr, nullptr, 393);
        logsoftmax_kernel<<<dim3(256), 1024, 0, stream>>>(logp);
    }
}

// Round 7
// 359.062 us; speedup vs baseline: 1.1967x; 1.0272x over previous
//
#include <hip/hip_runtime.h>

#define V_SIZE 50257
#define B_SIZE 256
#define S_LEN  15
#define H_DIM  512
#define NBLK_LG 786   // ceil(50257/64)

typedef __attribute__((ext_vector_type(8))) short bf16x8;
typedef __attribute__((ext_vector_type(4))) float f32x4;

__device__ __forceinline__ unsigned short f2bf(float f) {
    unsigned int u = __float_as_uint(f);
    u += 0x7fffu + ((u >> 16) & 1u);   // RNE
    return (unsigned short)(u >> 16);
}

// ---------------------------------------------------------------------------
// K2 (fused): per-b attention with u = h@attn_W computed inline; writes bf16
// x=[emb,ctx] and h. enc tile staged in LDS.
// ---------------------------------------------------------------------------
__global__ __launch_bounds__(256) void attn_kernel(
    const float* __restrict__ hidden, const float* __restrict__ enc,
    const int* __restrict__ tokens, const float* __restrict__ emb,
    const float* __restrict__ attn_W, float* __restrict__ attnw_out,
    unsigned short* __restrict__ x_bf, unsigned short* __restrict__ h_bf)
{
    const int b = blockIdx.x, tid = threadIdx.x;
    __shared__ float e_s[S_LEN][H_DIM];   // 30720 B
    __shared__ float h_sh[H_DIM];
    __shared__ float u_s[H_DIM];
    __shared__ float sc_s[S_LEN];
    __shared__ float w_s[S_LEN];
    {
        const float4* ev = (const float4*)(enc + (size_t)b * S_LEN * H_DIM);
        float4* es4 = (float4*)&e_s[0][0];
        #pragma unroll
        for (int i = 0; i < 8; ++i) {
            int idx = i * 256 + tid;
            if (idx < S_LEN * H_DIM / 4) es4[idx] = ev[idx];
        }
    }
    const float hv0 = hidden[(size_t)b * H_DIM + tid];
    const float hv1 = hidden[(size_t)b * H_DIM + tid + 256];
    h_sh[tid] = hv0; h_sh[tid + 256] = hv1;
    h_bf[(size_t)b * H_DIM + tid]       = f2bf(hv0);
    h_bf[(size_t)b * H_DIM + tid + 256] = f2bf(hv1);
    const int tok = tokens[b];
    x_bf[(size_t)b * 2 * H_DIM + tid]       = f2bf(emb[(size_t)tok * H_DIM + tid]);
    x_bf[(size_t)b * 2 * H_DIM + tid + 256] = f2bf(emb[(size_t)tok * H_DIM + tid + 256]);
    __syncthreads();
    // u[n] = sum_o h[o] * attn_W[o][n], n = tid and tid+256
    {
        float u0 = 0.f, u1 = 0.f;
        #pragma unroll 8
        for (int o = 0; o < H_DIM; ++o) {
            const float hs = h_sh[o];                    // LDS broadcast
            u0 += hs * attn_W[(size_t)o * H_DIM + tid];
            u1 += hs * attn_W[(size_t)o * H_DIM + tid + 256];
        }
        u_s[tid] = u0; u_s[tid + 256] = u1;
    }
    __syncthreads();
    const int wave = tid >> 6, lane = tid & 63;
    for (int s = wave; s < S_LEN; s += 4) {
        float acc = 0.f;
        #pragma unroll
        for (int k = 0; k < H_DIM / 64; ++k)
            acc += e_s[s][lane + k * 64] * u_s[lane + k * 64];
        #pragma unroll
        for (int off = 32; off; off >>= 1) acc += __shfl_down(acc, off);
        if (lane == 0) sc_s[s] = acc;
    }
    __syncthreads();
    float mx = -1e30f;
    for (int s = 0; s < S_LEN; ++s) mx = fmaxf(mx, sc_s[s]);
    float sum = 0.f;
    for (int s = 0; s < S_LEN; ++s) sum += __expf(sc_s[s] - mx);
    const float inv = 1.f / sum;
    if (tid < S_LEN) {
        float w = __expf(sc_s[tid] - mx) * inv;
        w_s[tid] = w;
        attnw_out[b * S_LEN + tid] = w;
    }
    __syncthreads();
    #pragma unroll
    for (int hh = 0; hh < 2; ++hh) {
        int h = tid + hh * 256;
        float c = 0.f;
        #pragma unroll
        for (int s = 0; s < S_LEN; ++s)
            c += w_s[s] * e_s[s][h];
        x_bf[(size_t)b * 2 * H_DIM + H_DIM + h] = f2bf(c);
    }
}

// ---------------------------------------------------------------------------
// Small NT MFMA GEMM: C = A(bf16) * B(f32->bf16)^T + bias
// ---------------------------------------------------------------------------
struct GemmP {
    const unsigned short* A; const float* B; const float* bias; float* C;
    int N; int K;
};

template<int BM, int BN, int BK, int WR, int WC>
__global__ __launch_bounds__(256) void gemm_nt(GemmP p0, GemmP p1)
{
    GemmP p = (blockIdx.z == 0) ? p0 : p1;
    constexpr int LDA = BK + 8;
    __shared__ __align__(16) unsigned short As[BM][LDA];
    __shared__ __align__(16) unsigned short Bs[BN][LDA];
    const int tid = threadIdx.x;
    const int bn0 = blockIdx.x * BN;
    const int bm0 = blockIdx.y * BM;
    const int wave = tid >> 6, lane = tid & 63;
    const int wm = (wave / WC) * (BM / WR);
    const int wn = (wave % WC) * (BN / WC);
    constexpr int MF = BM / WR / 16, NF = BN / WC / 16;
    const int n16 = lane & 15, quad = lane >> 4;

    f32x4 acc[MF][NF] = {};

    for (int k0 = 0; k0 < p.K; k0 += BK) {
        #pragma unroll
        for (int it = 0; it < BM / 32; ++it) {
            int v = it * 256 + tid;
            int row = v >> 3, seg = v & 7;
            *(uint4*)&As[row][seg * 8] =
                *(const uint4*)(p.A + (size_t)(bm0 + row) * p.K + k0 + seg * 8);
        }
        #pragma unroll
        for (int it = 0; it < BN / 32; ++it) {
            int v = it * 256 + tid;
            int row = v >> 3, seg = v & 7;
            int gv = bn0 + row;
            float4 w0 = make_float4(0, 0, 0, 0), w1 = make_float4(0, 0, 0, 0);
            if (gv < p.N) {
                const float4* src = (const float4*)(p.B + (size_t)gv * p.K + k0 + seg * 8);
                w0 = src[0]; w1 = src[1];
            }
            uint4 pk;
            pk.x = (unsigned)f2bf(w0.x) | ((unsigned)f2bf(w0.y) << 16);
            pk.y = (unsigned)f2bf(w0.z) | ((unsigned)f2bf(w0.w) << 16);
            pk.z = (unsigned)f2bf(w1.x) | ((unsigned)f2bf(w1.y) << 16);
            pk.w = (unsigned)f2bf(w1.z) | ((unsigned)f2bf(w1.w) << 16);
            *(uint4*)&Bs[row][seg * 8] = pk;
        }
        __syncthreads();
        #pragma unroll
        for (int kk = 0; kk < BK; kk += 32) {
            bf16x8 af[MF], bfr[NF];
            #pragma unroll
            for (int i = 0; i < MF; ++i)
                af[i] = *(const bf16x8*)&As[wm + i * 16 + n16][kk + quad * 8];
            #pragma unroll
            for (int j = 0; j < NF; ++j)
                bfr[j] = *(const bf16x8*)&Bs[wn + j * 16 + n16][kk + quad * 8];
            #pragma unroll
            for (int i = 0; i < MF; ++i)
                #pragma unroll
                for (int j = 0; j < NF; ++j)
                    acc[i][j] = __builtin_amdgcn_mfma_f32_16x16x32_bf16(
                        af[i], bfr[j], acc[i][j], 0, 0, 0);
        }
        __syncthreads();
    }
    #pragma unroll
    for (int i = 0; i < MF; ++i) {
        const int r0 = bm0 + wm + i * 16 + quad * 4;
        #pragma unroll
        for (int j = 0; j < NF; ++j) {
            const int c = bn0 + wn + j * 16 + n16;
            if (c < p.N) {
                const float bv = p.bias[c];
                #pragma unroll
                for (int r = 0; r < 4; ++r)
                    p.C[(size_t)(r0 + r) * p.N + c] = acc[i][j][r] + bv;
            }
        }
    }
}

// ---------------------------------------------------------------------------
// Logits GEMM, R6: r4 M-split grid (1572 blocks, co-XCD pairs) + T3/T14
// software pipeline. Double-buffered LDS (2x 17.4KB); per K-tile:
//   issue global loads for tile t+1   (in flight during compute)
//   compute tile t (ds_read + MFMA)
//   cvt+ds_write tile t+1 (vmcnt wait lands HERE, after compute)
//   one barrier
// HBM stage latency (~900cy) hides under the MFMA+ds_read phase instead of
// serializing with it. Reg cost: +32 VGPR staging (~110 total, 4 waves/SIMD).
// pm/ps layout pm[bx*256+row] unchanged.
// ---------------------------------------------------------------------------
template<bool PART>
__global__ __launch_bounds__(256, 4) void gemm_lg(
    const unsigned short* __restrict__ A, const float* __restrict__ B,
    const float* __restrict__ bias, float* __restrict__ C,
    float* __restrict__ pm, float* __restrict__ ps)
{
    constexpr int BN = 64, BK = 128;
    constexpr int LDB = BK + 8;              // 136 shorts = 272B pitch
    __shared__ __align__(16) unsigned short Bs[2][BN][LDB];
    const int tid = threadIdx.x;
    const int blk = blockIdx.x;
    int bx, by;
    if (blk < 1568) { int g = blk >> 4, s = blk & 15; bx = g * 8 + (s & 7); by = s >> 3; }
    else            { int s = blk - 1568;             bx = 784 + (s >> 1);  by = s & 1;  }
    const int bn0 = bx * BN;
    const int m0  = by * 128;                 // this block's 128 A-rows
    const int wave = tid >> 6, lane = tid & 63;
    const int wm = wave * 32;                 // wave-private 32 A-rows
    const int n16 = lane & 15, quad = lane >> 4;

    const int srow_base = tid >> 4;           // staging row (it*16 + this)
    const int sseg = tid & 15;                // staging 8-float segment

    float4 r0[4], r1[4];                      // in-flight staging registers
    auto LOAD = [&](int k0) {
        #pragma unroll
        for (int it = 0; it < 4; ++it) {
            int gv = bn0 + it * 16 + srow_base;
            if (gv < V_SIZE) {
                const float4* src = (const float4*)(B + (size_t)gv * H_DIM + k0 + sseg * 8);
                r0[it] = src[0]; r1[it] = src[1];
            } else {
                r0[it] = make_float4(0, 0, 0, 0); r1[it] = make_float4(0, 0, 0, 0);
            }
        }
    };
    auto CVTW = [&](int buf) {
        #pragma unroll
        for (int it = 0; it < 4; ++it) {
            uint4 pk;
            pk.x = (unsigned)f2bf(r0[it].x) | ((unsigned)f2bf(r0[it].y) << 16);
            pk.y = (unsigned)f2bf(r0[it].z) | ((unsigned)f2bf(r0[it].w) << 16);
            pk.z = (unsigned)f2bf(r1[it].x) | ((unsigned)f2bf(r1[it].y) << 16);
            pk.w = (unsigned)f2bf(r1[it].z) | ((unsigned)f2bf(r1[it].w) << 16);
            *(uint4*)&Bs[buf][it * 16 + srow_base][sseg * 8] = pk;
        }
    };

    f32x4 acc[2][4] = {};
    const unsigned short* arow[2];
    #pragma unroll
    for (int i = 0; i < 2; ++i)
        arow[i] = A + (size_t)(m0 + wm + i * 16 + n16) * H_DIM;

    // prologue: tile 0 staged the plain way
    LOAD(0);
    CVTW(0);
    __syncthreads();

    #pragma unroll
    for (int t = 0; t < 4; ++t) {
        const int k0 = t * BK;
        if (t < 3) LOAD(k0 + BK);             // issue-early: in flight during MFMA
        #pragma unroll
        for (int kk = 0; kk < BK; kk += 32) {
            bf16x8 af[2], bfr[4];
            #pragma unroll
            for (int i = 0; i < 2; ++i)
                af[i] = *(const bf16x8*)(arow[i] + k0 + kk + quad * 8);  // L2-hot A
            #pragma unroll
            for (int j = 0; j < 4; ++j)
                bfr[j] = *(const bf16x8*)&Bs[t & 1][j * 16 + n16][kk + quad * 8];
            #pragma unroll
            for (int i = 0; i < 2; ++i)
                #pragma unroll
                for (int j = 0; j < 4; ++j)
                    acc[i][j] = __builtin_amdgcn_mfma_f32_16x16x32_bf16(
                        af[i], bfr[j], acc[i][j], 0, 0, 0);
        }
        if (t < 3) {
            CVTW((t + 1) & 1);                // write-late: vmcnt wait after compute
            __syncthreads();
        }
    }

    // epilogue
    int cj[4]; float bvv[4]; bool okj[4];
    #pragma unroll
    for (int j = 0; j < 4; ++j) {
        cj[j] = bn0 + j * 16 + n16;
        okj[j] = cj[j] < V_SIZE;
        bvv[j] = okj[j] ? bias[cj[j]] : 0.f;
    }
    #pragma unroll
    for (int i = 0; i < 2; ++i) {
        const int r0i = wm + i * 16 + quad * 4;        // local row in [0,128)
        if (PART) {
            #pragma unroll
            for (int r = 0; r < 4; ++r) {
                float m = -1e30f;
                #pragma unroll
                for (int j = 0; j < 4; ++j)
                    if (okj[j]) m = fmaxf(m, acc[i][j][r] + bvv[j]);
                #pragma unroll
                for (int d = 1; d < 16; d <<= 1) m = fmaxf(m, __shfl_xor(m, d));
                float s = 0.f;
                #pragma unroll
                for (int j = 0; j < 4; ++j)
                    if (okj[j]) s += __expf(acc[i][j][r] + bvv[j] - m);
                #pragma unroll
                for (int d = 1; d < 16; d <<= 1) s += __shfl_xor(s, d);
                if (n16 == 0) {
                    pm[(size_t)bx * B_SIZE + m0 + r0i + r] = m;
                    ps[(size_t)bx * B_SIZE + m0 + r0i + r] = s;
                }
            }
        }
        #pragma unroll
        for (int j = 0; j < 4; ++j) if (okj[j]) {
            #pragma unroll
            for (int r = 0; r < 4; ++r)
                C[(size_t)(m0 + r0i + r) * V_SIZE + cj[j]] = acc[i][j][r] + bvv[j];
        }
    }
}

// ---------------------------------------------------------------------------
// K3c: GRU gate math (fp32), writes h_new (f32 to d_out) + bf16 copy for GEMM
// ---------------------------------------------------------------------------
__global__ __launch_bounds__(256) void gru_kernel(
    const float* __restrict__ gi, const float* __restrict__ gh,
    const float* __restrict__ hidden, float* __restrict__ hnew_out,
    unsigned short* __restrict__ hnew_bf)
{
    const int idx = blockIdx.x * 256 + threadIdx.x;   // < 131072
    const int b = idx >> 9, h = idx & 511;
    const float* gib = gi + (size_t)b * 3 * H_DIM;
    const float* ghb = gh + (size_t)b * 3 * H_DIM;
    float r = 1.f / (1.f + __expf(-(gib[h] + ghb[h])));
    float z = 1.f / (1.f + __expf(-(gib[H_DIM + h] + ghb[H_DIM + h])));
    float n = gib[2 * H_DIM + h] + r * ghb[2 * H_DIM + h];
    n = 1.f - 2.f / (1.f + __expf(2.f * n));          // tanh
    float hp = hidden[idx];
    float hn = (1.f - z) * n + z * hp;
    hnew_out[idx] = hn;
    hnew_bf[idx] = f2bf(hn);
}

// ---------------------------------------------------------------------------
// K5: combine 786 partials/row -> lse, subtract over this block's V-half.
// grid (256 rows, 2 halves), block 1024, float4-vectorized subtract.
// ---------------------------------------------------------------------------
__global__ __launch_bounds__(1024) void finalize_kernel(
    float* __restrict__ logits, const float* __restrict__ pm,
    const float* __restrict__ ps)
{
    const int b = blockIdx.x, tid = threadIdx.x;
    float m = -1e30f, s = 0.f;
    for (int i = tid; i < NBLK_LG; i += 1024) {
        float mm = pm[(size_t)i * B_SIZE + b], ss = ps[(size_t)i * B_SIZE + b];
        float nm = fmaxf(m, mm);
        s = s * __expf(m - nm) + ss * __expf(mm - nm);
        m = nm;
    }
    const int lane = tid & 63, wave = tid >> 6;
    #pragma unroll
    for (int off = 32; off; off >>= 1) {
        float m2 = __shfl_down(m, off), s2 = __shfl_down(s, off);
        float nm = fmaxf(m, m2);
        s = s * __expf(m - nm) + s2 * __expf(m2 - nm);
        m = nm;
    }
    __shared__ float msh[16], ssh[16], lse_sh;
    if (lane == 0) { msh[wave] = m; ssh[wave] = s; }
    __syncthreads();
    if (tid == 0) {
        float M = msh[0], S = ssh[0];
        for (int w = 1; w < 16; ++w) {
            float nm = fmaxf(M, msh[w]);
            S = S * __expf(M - nm) + ssh[w] * __expf(msh[w] - nm);
            M = nm;
        }
        lse_sh = M + logf(S);
    }
    __syncthreads();
    const float lse = lse_sh;
    constexpr int HALF = 25132;               // multiple of 4
    const int start = blockIdx.y * HALF;
    const int end = min(V_SIZE, start + HALF);
    float* p0 = logits + (size_t)b * V_SIZE + start;
    const int n = end - start;
    const int mis = (int)(((uintptr_t)p0 >> 2) & 3);
    int pre = mis ? (4 - mis) : 0; if (pre > n) pre = n;
    if (tid < pre) p0[tid] -= lse;
    const int nvec = (n - pre) >> 2;
    float4* rv = (float4*)(p0 + pre);
    for (int i = tid; i < nvec; i += 1024) {
        float4 v = rv[i];
        v.x -= lse; v.y -= lse; v.z -= lse; v.w -= lse;
        rv[i] = v;
    }
    const int rem = n - pre - (nvec << 2);
    if (tid < rem) p0[pre + (nvec << 2) + tid] -= lse;
}

// fallback: two-pass log-softmax (only if ws too small for partials)
__global__ __launch_bounds__(1024) void logsoftmax_kernel(float* __restrict__ logits)
{
    const int b = blockIdx.x, tid = threadIdx.x;
    float* row = logits + (size_t)b * V_SIZE;
    float m = -1e30f, s = 0.f;
    for (int c = tid; c < V_SIZE; c += 1024) {
        float x = row[c];
        float nm = fmaxf(m, x);
        s = s * __expf(m - nm) + __expf(x - nm);
        m = nm;
    }
    const int lane = tid & 63, wave = tid >> 6;
    #pragma unroll
    for (int off = 32; off; off >>= 1) {
        float m2 = __shfl_down(m, off), s2 = __shfl_down(s, off);
        float nm = fmaxf(m, m2);
        s = s * __expf(m - nm) + s2 * __expf(m2 - nm);
        m = nm;
    }
    __shared__ float msh[16], ssh[16], lse_sh;
    if (lane == 0) { msh[wave] = m; ssh[wave] = s; }
    __syncthreads();
    if (tid == 0) {
        float M = msh[0], S = ssh[0];
        for (int w = 1; w < 16; ++w) {
            float nm = fmaxf(M, msh[w]);
            S = S * __expf(M - nm) + ssh[w] * __expf(msh[w] - nm);
            M = nm;
        }
        lse_sh = M + logf(S);
    }
    __syncthreads();
    const float lse = lse_sh;
    for (int c = tid; c < V_SIZE; c += 1024) row[c] -= lse;
}

// ---------------------------------------------------------------------------
// workspace layout (bytes)
// ---------------------------------------------------------------------------
constexpr size_t OFF_XBF    = 524288;    // 256*1024*2 = 524288
constexpr size_t OFF_HBF    = 1048576;   // 256*512*2  = 262144
constexpr size_t OFF_HNEWBF = 1310720;   // 262144
constexpr size_t OFF_GI     = 1572864;   // 256*1536*4 = 1572864
constexpr size_t OFF_GH     = 3145728;   // 1572864
constexpr size_t OFF_PM     = 4718592;   // 786*256*4  = 804864
constexpr size_t OFF_PS     = 5523456;   // 804864
constexpr size_t WS_NEED    = 6328320;

extern "C" void kernel_launch(void* const* d_in, const int* in_sizes, int n_in,
                              void* d_out, int out_size, void* d_ws, size_t ws_size,
                              hipStream_t stream) {
    const int*   tokens = (const int*)d_in[0];
    const float* hidden = (const float*)d_in[1];
    const float* enc    = (const float*)d_in[2];
    const float* emb    = (const float*)d_in[3];
    const float* attn_W = (const float*)d_in[4];
    // d_in[5] = attn_b: constant across s -> cancels in softmax; unused
    const float* W_ih   = (const float*)d_in[6];
    const float* W_hh   = (const float*)d_in[7];
    const float* b_ih   = (const float*)d_in[8];
    const float* b_hh   = (const float*)d_in[9];
    const float* out_W  = (const float*)d_in[10];
    const float* out_b  = (const float*)d_in[11];

    float* out = (float*)d_out;
    float* logp      = out;                                   // [256][50257]
    float* hnew_out  = out + (size_t)B_SIZE * V_SIZE;         // [256][512]
    float* attnw_out = hnew_out + (size_t)B_SIZE * H_DIM;     // [256][15]

    char* ws = (char*)d_ws;
    unsigned short* x_bf    = (unsigned short*)(ws + OFF_XBF);
    unsigned short* h_bf    = (unsigned short*)(ws + OFF_HBF);
    unsigned short* hnew_bf = (unsigned short*)(ws + OFF_HNEWBF);
    float*          gi_ws   = (float*)(ws + OFF_GI);
    float*          gh_ws   = (float*)(ws + OFF_GH);
    float*          pm_ws   = (float*)(ws + OFF_PM);
    float*          ps_ws   = (float*)(ws + OFF_PS);

    attn_kernel<<<dim3(256), 256, 0, stream>>>(hidden, enc, tokens, emb, attn_W,
                                               attnw_out, x_bf, h_bf);
    GemmP gi_p { x_bf, W_ih, b_ih, gi_ws, 3 * H_DIM, 2 * H_DIM };
    GemmP gh_p { h_bf, W_hh, b_hh, gh_ws, 3 * H_DIM, H_DIM };
    gemm_nt<64, 64, 64, 2, 2><<<dim3(24, 4, 2), 256, 0, stream>>>(gi_p, gh_p);
    gru_kernel<<<dim3(512), 256, 0, stream>>>(gi_ws, gh_ws, hidden, hnew_out, hnew_bf);

    if (ws_size >= WS_NEED) {
        gemm_lg<true><<<dim3(2 * NBLK_LG), 256, 0, stream>>>(
            hnew_bf, out_W, out_b, logp, pm_ws, ps_ws);
        finalize_kernel<<<dim3(256, 2), 1024, 0, stream>>>(logp, pm_ws, ps_ws);
    } else {
        gemm_lg<false><<<dim3(2 * NBLK_LG), 256, 0, stream>>>(
            hnew_bf, out_W, out_b, logp, nullptr, nullptr);
        logsoftmax_kernel<<<dim3(256), 1024, 0, stream>>>(logp);
    }
}